// Round 7
// baseline (60.511 us; speedup 1.0000x reference)
//
#include <hip/hip_runtime.h>
#include <hip/hip_bf16.h>

#define N_NODES 4096
#define F_IN 512
#define FHD 64
#define H_HEADS 8
#define C_OUT 512   /* H*FH */
#define ALPHA 0.2f
#define MAXE 192

typedef __attribute__((ext_vector_type(8))) short bf16x8;
typedef __attribute__((ext_vector_type(4))) float f32x4;

static __device__ __forceinline__ unsigned short f2bf(float f) {
  __hip_bfloat16 h = __float2bfloat16(f);
  union { __hip_bfloat16 h; unsigned short u; } cvt;
  cvt.h = h;
  return cvt.u;
}
static __device__ __forceinline__ float bf2f(unsigned short u) {
  return __uint_as_float(((unsigned)u) << 16);
}

// ---------------------------------------------------------------------------
// conv: blocks [0,2048) X->bf16 | [2048,2112) W transpose->bf16 | 2112 zero
// colsum. Small, fully independent streaming work.
// ---------------------------------------------------------------------------
__global__ __launch_bounds__(256) void conv_kernel(
    const float* __restrict__ X, const float* __restrict__ W,
    unsigned short* __restrict__ Xb, unsigned short* __restrict__ WbT,
    float* __restrict__ colsum) {
  __shared__ float sT[64][65];
  const int bid = blockIdx.x;
  const int tid = threadIdx.x;
  if (bid < 2048) {
    int idx = bid * 256 + tid;  // 4 elems/thread
    float4 v = reinterpret_cast<const float4*>(X)[idx];
    ushort4 u;
    u.x = f2bf(v.x); u.y = f2bf(v.y); u.z = f2bf(v.z); u.w = f2bf(v.w);
    reinterpret_cast<ushort4*>(Xb)[idx] = u;
  } else if (bid < 2048 + 64) {
    const int b2 = bid - 2048;
    const int fblk = b2 & 7, h = b2 >> 3;
#pragma unroll
    for (int i = 0; i < 16; ++i) {
      int idx = tid + i * 256;
      int f = idx >> 6, o = idx & 63;
      sT[f][o] = W[((size_t)h * F_IN + fblk * 64 + f) * FHD + o];
    }
    __syncthreads();
#pragma unroll
    for (int i = 0; i < 16; ++i) {
      int idx = tid + i * 256;
      int o = idx >> 6, f = idx & 63;
      WbT[(size_t)h * FHD * F_IN + (size_t)o * F_IN + fblk * 64 + f] =
          f2bf(sT[f][o]);
    }
  } else {
    colsum[tid] = 0.f;
    colsum[tid + 256] = 0.f;
  }
}

// ---------------------------------------------------------------------------
// MFMA GEMM v2: 64 rows x 1 head per block, BK=64, grid (64,8)=512 blocks
// -> 2 blocks/CU, 2 waves/SIMD (v1 ran 1 wave/SIMD: latency exposed).
// Fused: s_self/s_neigh scores + colsum partials (atomicAdd).
// A frag: row=l&15, k=(l>>4)*8+j ; B frag: col=l&15, k=(l>>4)*8+j
// C/D:    col=l&15, row=(l>>4)*4+reg   [m89/m91-verified]
// ---------------------------------------------------------------------------
__global__ __launch_bounds__(256) void gemm_feats_mfma_kernel(
    const unsigned short* __restrict__ Xb, const unsigned short* __restrict__ WbT,
    const float* __restrict__ a_self, const float* __restrict__ a_neigh,
    unsigned short* __restrict__ featsb,
    float* __restrict__ s_self, float* __restrict__ s_neigh,
    float* __restrict__ colsum) {
  const int h = blockIdx.y;
  const int n0 = blockIdx.x * 64;
  __shared__ unsigned short sX[2][64 * 72];  // 64 k padded ->72 (144B, 16B-align)
  __shared__ unsigned short sW[2][64 * 72];
  __shared__ float sred[4][64];
  const int tid = threadIdx.x;
  const int wid = tid >> 6, lane = tid & 63;
  const int l15 = lane & 15, l4 = lane >> 4;

  // staging: thread t -> row t>>2, 16-el segment (t&3)*16  (32 B/thread)
  const int row = tid >> 2, seg = (tid & 3) * 16;
  const unsigned short* xsrc = Xb + (size_t)(n0 + row) * F_IN + seg;
  const unsigned short* wsrc = WbT + ((size_t)h * FHD + row) * F_IN + seg;
  const int soff = row * 72 + seg;

  f32x4 acc[4];
#pragma unroll
  for (int j = 0; j < 4; ++j) acc[j] = (f32x4){0.f, 0.f, 0.f, 0.f};

  // prologue: stage K-step 0
  *(bf16x8*)&sX[0][soff] = *(const bf16x8*)(xsrc);
  *(bf16x8*)&sX[0][soff + 8] = *(const bf16x8*)(xsrc + 8);
  *(bf16x8*)&sW[0][soff] = *(const bf16x8*)(wsrc);
  *(bf16x8*)&sW[0][soff + 8] = *(const bf16x8*)(wsrc + 8);
  __syncthreads();

  int cur = 0;
  for (int s = 0; s < 8; ++s) {
    bf16x8 px0, px1, pw0, pw1;
    const bool pf = (s < 7);
    if (pf) {
      const int k = (s + 1) * 64;
      px0 = *(const bf16x8*)(xsrc + k);
      px1 = *(const bf16x8*)(xsrc + k + 8);
      pw0 = *(const bf16x8*)(wsrc + k);
      pw1 = *(const bf16x8*)(wsrc + k + 8);
    }
#pragma unroll
    for (int kk = 0; kk < 2; ++kk) {
      bf16x8 a = *(const bf16x8*)&sX[cur][(wid * 16 + l15) * 72 + kk * 32 + l4 * 8];
#pragma unroll
      for (int tn = 0; tn < 4; ++tn) {
        bf16x8 b = *(const bf16x8*)&sW[cur][(tn * 16 + l15) * 72 + kk * 32 + l4 * 8];
        acc[tn] =
            __builtin_amdgcn_mfma_f32_16x16x32_bf16(a, b, acc[tn], 0, 0, 0);
      }
    }
    if (pf) {
      *(bf16x8*)&sX[cur ^ 1][soff] = px0;
      *(bf16x8*)&sX[cur ^ 1][soff + 8] = px1;
      *(bf16x8*)&sW[cur ^ 1][soff] = pw0;
      *(bf16x8*)&sW[cur ^ 1][soff + 8] = pw1;
      __syncthreads();
      cur ^= 1;
    }
  }

  // epilogue: bf16 feats stores + fused score dot-products
  float aS[4], aN[4];
#pragma unroll
  for (int tn = 0; tn < 4; ++tn) {
    aS[tn] = a_self[h * FHD + tn * 16 + l15];
    aN[tn] = a_neigh[h * FHD + tn * 16 + l15];
  }
#pragma unroll
  for (int r = 0; r < 4; ++r) {
    const int grow = n0 + wid * 16 + l4 * 4 + r;
#pragma unroll
    for (int tn = 0; tn < 4; ++tn)
      featsb[(size_t)grow * C_OUT + h * FHD + tn * 16 + l15] =
          f2bf(acc[tn][r]);
    float ps = 0.f, pn = 0.f;
#pragma unroll
    for (int tn = 0; tn < 4; ++tn) {
      float v = acc[tn][r];
      ps = fmaf(v, aS[tn], ps);
      pn = fmaf(v, aN[tn], pn);
    }
#pragma unroll
    for (int sh = 1; sh < 16; sh <<= 1) {
      ps += __shfl_xor(ps, sh, 64);
      pn += __shfl_xor(pn, sh, 64);
    }
    if (l15 == 0) {
      s_self[grow * 8 + h] = ps;
      s_neigh[grow * 8 + h] = pn;
    }
  }

  // fused colsum partial: sum over r; shfl over l4 groups; cross-wave LDS;
  // 64 atomicAdds per block (64 adders per address total).
  float psum[4];
#pragma unroll
  for (int tn = 0; tn < 4; ++tn) {
    float s = acc[tn][0] + acc[tn][1] + acc[tn][2] + acc[tn][3];
    s += __shfl_xor(s, 16, 64);
    s += __shfl_xor(s, 32, 64);
    psum[tn] = s;
  }
  if (l4 == 0) {
#pragma unroll
    for (int tn = 0; tn < 4; ++tn) sred[wid][tn * 16 + l15] = psum[tn];
  }
  __syncthreads();
  if (tid < 64) {
    float s = sred[0][tid] + sred[1][tid] + sred[2][tid] + sred[3][tid];
    atomicAdd(&colsum[h * FHD + tid], s);
  }
}

// ---------------------------------------------------------------------------
// attn: one block (256 thr) per row i. Fused A-row scan (HBM) overlaps the
// feats gather (L2) across the 8 resident blocks/CU.
// ---------------------------------------------------------------------------
__global__ __launch_bounds__(256) void attn_kernel(
    const float* __restrict__ A, const unsigned short* __restrict__ featsb,
    const float* __restrict__ s_self, const float* __restrict__ s_neigh,
    const float* __restrict__ colsum, const float* __restrict__ bias,
    float* __restrict__ out) {
  const int i = blockIdx.x;
  const int tid = threadIdx.x;
  const int wid = tid >> 6, lane = tid & 63;
  __shared__ int s_idx[MAXE];
  __shared__ float s_w[MAXE][9];
  __shared__ int wave_tot[4];
  __shared__ float sh_self[8];
  __shared__ float sh_e0[8], sh_invZ[8];

  if (tid < 8) sh_self[tid] = s_self[i * 8 + tid];

  // ---- Phase 1: fused CSR scan; thread owns 16 consecutive elements
  const float4* __restrict__ Arow4 =
      reinterpret_cast<const float4*>(A + (size_t)i * N_NODES);
  float4 v[4];
#pragma unroll
  for (int q = 0; q < 4; ++q) v[q] = Arow4[tid * 4 + q];
  int mask16 = 0;
#pragma unroll
  for (int q = 0; q < 4; ++q) {
    mask16 |= (v[q].x != 0.f) ? (1 << (q * 4 + 0)) : 0;
    mask16 |= (v[q].y != 0.f) ? (1 << (q * 4 + 1)) : 0;
    mask16 |= (v[q].z != 0.f) ? (1 << (q * 4 + 2)) : 0;
    mask16 |= (v[q].w != 0.f) ? (1 << (q * 4 + 3)) : 0;
  }
  int cnt = __popc(mask16);
  int inc = cnt;
#pragma unroll
  for (int s = 1; s < 64; s <<= 1) {
    int t = __shfl_up(inc, s, 64);
    if (lane >= s) inc += t;
  }
  if (lane == 63) wave_tot[wid] = inc;
  __syncthreads();
  int wprefix = 0, tot = 0;
#pragma unroll
  for (int w = 0; w < 4; ++w) {
    int t = wave_tot[w];
    if (w < wid) wprefix += t;
    tot += t;
  }
  int pos = wprefix + inc - cnt;
  const int jbase = tid * 16;
  while (mask16) {
    int k = __ffs(mask16) - 1;
    mask16 &= mask16 - 1;
    if (pos < MAXE) s_idx[pos] = jbase + k;
    ++pos;
  }
  const int deg = tot < MAXE ? tot : MAXE;
  __syncthreads();

  // ---- Phase 2: raw LeakyReLU logits per (edge, head)
  for (int k = tid; k < deg * 8; k += 256) {
    int e = k >> 3, h = k & 7;
    int j = s_idx[e];
    float l = sh_self[h] + s_neigh[j * 8 + h];
    s_w[e][h] = l > 0.f ? l : ALPHA * l;
  }
  __syncthreads();

  // ---- Phase 3: per-head softmax stats; wave wid owns heads 2wid,2wid+1
#pragma unroll
  for (int p = 0; p < 2; ++p) {
    const int h = wid * 2 + p;
    float m = -1e30f;
    for (int e = lane; e < deg; e += 64) m = fmaxf(m, s_w[e][h]);
#pragma unroll
    for (int s = 32; s > 0; s >>= 1) m = fmaxf(m, __shfl_xor(m, s, 64));
    m = fmaxf(m, 0.0f);  // non-edge dense entries are exactly 0
    float e0 = __expf(-m);
    float zs = 0.f;
    for (int e = lane; e < deg; e += 64) {
      float w = __expf(s_w[e][h] - m);
      s_w[e][h] = w - e0;  // edge weight minus colsum-correction share
      zs += w;
    }
#pragma unroll
    for (int s = 32; s > 0; s >>= 1) zs += __shfl_xor(zs, s, 64);
    if (lane == 0) {
      sh_e0[h] = e0;
      sh_invZ[h] = 1.0f / (zs + (float)(N_NODES - deg) * e0);
    }
  }
  __syncthreads();

  // ---- Phase 4: thread owns columns (2tid, 2tid+1); 8 FMA chains, unroll 4
  const int h = tid >> 5;
  const float e0 = sh_e0[h], invZ = sh_invZ[h];
  const float2 cs = *reinterpret_cast<const float2*>(&colsum[tid * 2]);
  const ushort2* __restrict__ fb = reinterpret_cast<const ushort2*>(featsb);
  float ax0 = e0 * cs.x, ay0 = e0 * cs.y;
  float ax1 = 0.f, ay1 = 0.f, ax2 = 0.f, ay2 = 0.f, ax3 = 0.f, ay3 = 0.f;
  int e = 0;
  for (; e + 3 < deg; e += 4) {
    int j0 = s_idx[e], j1 = s_idx[e + 1], j2 = s_idx[e + 2], j3 = s_idx[e + 3];
    float w0 = s_w[e][h], w1 = s_w[e + 1][h];
    float w2 = s_w[e + 2][h], w3 = s_w[e + 3][h];
    ushort2 u0 = fb[(size_t)j0 * 256 + tid];
    ushort2 u1 = fb[(size_t)j1 * 256 + tid];
    ushort2 u2 = fb[(size_t)j2 * 256 + tid];
    ushort2 u3 = fb[(size_t)j3 * 256 + tid];
    ax0 = fmaf(w0, bf2f(u0.x), ax0);
    ay0 = fmaf(w0, bf2f(u0.y), ay0);
    ax1 = fmaf(w1, bf2f(u1.x), ax1);
    ay1 = fmaf(w1, bf2f(u1.y), ay1);
    ax2 = fmaf(w2, bf2f(u2.x), ax2);
    ay2 = fmaf(w2, bf2f(u2.y), ay2);
    ax3 = fmaf(w3, bf2f(u3.x), ax3);
    ay3 = fmaf(w3, bf2f(u3.y), ay3);
  }
  for (; e < deg; ++e) {
    float w0 = s_w[e][h];
    ushort2 u0 = fb[(size_t)s_idx[e] * 256 + tid];
    ax0 = fmaf(w0, bf2f(u0.x), ax0);
    ay0 = fmaf(w0, bf2f(u0.y), ay0);
  }
  const float2 bb = *reinterpret_cast<const float2*>(&bias[tid * 2]);
  float vx = ((ax0 + ax1) + (ax2 + ax3)) * invZ + bb.x;
  float vy = ((ay0 + ay1) + (ay2 + ay3)) * invZ + bb.y;
  float2 o;
  o.x = vx > 0.f ? vx : 0.f;
  o.y = vy > 0.f ? vy : 0.f;
  *reinterpret_cast<float2*>(&out[(size_t)i * C_OUT + tid * 2]) = o;
}

extern "C" void kernel_launch(void* const* d_in, const int* in_sizes, int n_in,
                              void* d_out, int out_size, void* d_ws, size_t ws_size,
                              hipStream_t stream) {
  const float* X = (const float*)d_in[0];
  const float* A = (const float*)d_in[1];
  const float* W = (const float*)d_in[2];
  const float* a_self = (const float*)d_in[3];
  const float* a_neigh = (const float*)d_in[4];
  const float* b = (const float*)d_in[5];
  float* out = (float*)d_out;

  char* ws = (char*)d_ws;
  unsigned short* featsb = (unsigned short*)ws;               // 4 MB
  char* p = ws + (size_t)N_NODES * C_OUT * 2;
  float* s_self = (float*)p;  p += N_NODES * H_HEADS * 4;     // 128 KB
  float* s_neigh = (float*)p; p += N_NODES * H_HEADS * 4;     // 128 KB
  float* colsum = (float*)p;  p += C_OUT * 4;                 // 2 KB
  unsigned short* WbT = (unsigned short*)p;                   // 512 KB

  // Xb parked in d_out (4 MB of its 8 MB); attn fully overwrites d_out later.
  unsigned short* Xb = (unsigned short*)d_out;

  conv_kernel<<<2048 + 64 + 1, 256, 0, stream>>>(X, W, Xb, WbT, colsum);
  gemm_feats_mfma_kernel<<<dim3(64, 8), 256, 0, stream>>>(
      Xb, WbT, a_self, a_neigh, featsb, s_self, s_neigh, colsum);
  attn_kernel<<<N_NODES, 256, 0, stream>>>(A, featsb, s_self, s_neigh, colsum,
                                           b, out);
}

// Round 8
// 55.755 us; speedup vs baseline: 1.0853x; 1.0853x over previous
//
#include <hip/hip_runtime.h>
#include <hip/hip_bf16.h>

#define N_NODES 4096
#define F_IN 512
#define FHD 64
#define H_HEADS 8
#define C_OUT 512   /* H*FH */
#define ALPHA 0.2f
#define MAXE 192
#define GEMM_BLOCKS 512  /* 64 rowblks x 8 heads */

typedef __attribute__((ext_vector_type(8))) short bf16x8;
typedef __attribute__((ext_vector_type(4))) float f32x4;

static __device__ __forceinline__ unsigned short f2bf(float f) {
  __hip_bfloat16 h = __float2bfloat16(f);
  union { __hip_bfloat16 h; unsigned short u; } cvt;
  cvt.h = h;
  return cvt.u;
}
static __device__ __forceinline__ float bf2f(unsigned short u) {
  return __uint_as_float(((unsigned)u) << 16);
}

// ---------------------------------------------------------------------------
// conv: blocks [0,2048) X->bf16 | [2048,2112) W transpose->bf16 | 2112 zero
// colsum.
// ---------------------------------------------------------------------------
__global__ __launch_bounds__(256) void conv_kernel(
    const float* __restrict__ X, const float* __restrict__ W,
    unsigned short* __restrict__ Xb, unsigned short* __restrict__ WbT,
    float* __restrict__ colsum) {
  __shared__ float sT[64][65];
  const int bid = blockIdx.x;
  const int tid = threadIdx.x;
  if (bid < 2048) {
    int idx = bid * 256 + tid;  // 4 elems/thread
    float4 v = reinterpret_cast<const float4*>(X)[idx];
    ushort4 u;
    u.x = f2bf(v.x); u.y = f2bf(v.y); u.z = f2bf(v.z); u.w = f2bf(v.w);
    reinterpret_cast<ushort4*>(Xb)[idx] = u;
  } else if (bid < 2048 + 64) {
    const int b2 = bid - 2048;
    const int fblk = b2 & 7, h = b2 >> 3;
#pragma unroll
    for (int i = 0; i < 16; ++i) {
      int idx = tid + i * 256;
      int f = idx >> 6, o = idx & 63;
      sT[f][o] = W[((size_t)h * F_IN + fblk * 64 + f) * FHD + o];
    }
    __syncthreads();
#pragma unroll
    for (int i = 0; i < 16; ++i) {
      int idx = tid + i * 256;
      int o = idx >> 6, f = idx & 63;
      WbT[(size_t)h * FHD * F_IN + (size_t)o * F_IN + fblk * 64 + f] =
          f2bf(sT[f][o]);
    }
  } else {
    colsum[tid] = 0.f;
    colsum[tid + 256] = 0.f;
  }
}

// ---------------------------------------------------------------------------
// gemm_scan: blocks [0,512) = MFMA GEMM (64 rows x 1 head, BK=64, dbuf);
// blocks [512, 512+4096) = A-row CSR scan (pure HBM streaming).
// Independent work co-resident on CUs -> scan's HBM traffic overlaps the
// GEMM's MFMA/LDS phases (R7's in-block fusion failed to get this).
// ---------------------------------------------------------------------------
__global__ __launch_bounds__(256) void gemm_scan_kernel(
    const unsigned short* __restrict__ Xb, const unsigned short* __restrict__ WbT,
    const float* __restrict__ a_self, const float* __restrict__ a_neigh,
    const float* __restrict__ A,
    unsigned short* __restrict__ featsb,
    float* __restrict__ s_self, float* __restrict__ s_neigh,
    float* __restrict__ colsum,
    unsigned short* __restrict__ edges, int* __restrict__ degs) {
  __shared__ unsigned short sX[2][64 * 72];  // k padded 64->72 (16B-aligned)
  __shared__ unsigned short sW[2][64 * 72];
  __shared__ float sred[4][64];              // scan path aliases wave_tot here
  const int bid = blockIdx.x;
  const int tid = threadIdx.x;
  const int wid = tid >> 6, lane = tid & 63;

  if (bid >= GEMM_BLOCKS) {
    // ================= scan path: CSR build for row i =================
    const int i = bid - GEMM_BLOCKS;
    int* wave_tot = reinterpret_cast<int*>(&sred[0][0]);
    const float4* __restrict__ Arow4 =
        reinterpret_cast<const float4*>(A + (size_t)i * N_NODES);
    float4 v[4];
#pragma unroll
    for (int q = 0; q < 4; ++q) v[q] = Arow4[tid * 4 + q];
    int mask16 = 0;
#pragma unroll
    for (int q = 0; q < 4; ++q) {
      mask16 |= (v[q].x != 0.f) ? (1 << (q * 4 + 0)) : 0;
      mask16 |= (v[q].y != 0.f) ? (1 << (q * 4 + 1)) : 0;
      mask16 |= (v[q].z != 0.f) ? (1 << (q * 4 + 2)) : 0;
      mask16 |= (v[q].w != 0.f) ? (1 << (q * 4 + 3)) : 0;
    }
    int cnt = __popc(mask16);
    int inc = cnt;
#pragma unroll
    for (int s = 1; s < 64; s <<= 1) {
      int t = __shfl_up(inc, s, 64);
      if (lane >= s) inc += t;
    }
    if (lane == 63) wave_tot[wid] = inc;
    __syncthreads();
    int wprefix = 0, tot = 0;
#pragma unroll
    for (int w = 0; w < 4; ++w) {
      int t = wave_tot[w];
      if (w < wid) wprefix += t;
      tot += t;
    }
    int pos = wprefix + inc - cnt;
    const int jbase = tid * 16;
    unsigned short* __restrict__ erow = edges + (size_t)i * MAXE;
    while (mask16) {
      int k = __ffs(mask16) - 1;
      mask16 &= mask16 - 1;
      if (pos < MAXE) erow[pos] = (unsigned short)(jbase + k);
      ++pos;
    }
    if (tid == 0) degs[i] = tot < MAXE ? tot : MAXE;
    return;
  }

  // ================= GEMM path =================
  const int h = bid >> 6;
  const int n0 = (bid & 63) * 64;
  const int l15 = lane & 15, l4 = lane >> 4;

  const int row = tid >> 2, seg = (tid & 3) * 16;
  const unsigned short* xsrc = Xb + (size_t)(n0 + row) * F_IN + seg;
  const unsigned short* wsrc = WbT + ((size_t)h * FHD + row) * F_IN + seg;
  const int soff = row * 72 + seg;

  f32x4 acc[4];
#pragma unroll
  for (int j = 0; j < 4; ++j) acc[j] = (f32x4){0.f, 0.f, 0.f, 0.f};

  *(bf16x8*)&sX[0][soff] = *(const bf16x8*)(xsrc);
  *(bf16x8*)&sX[0][soff + 8] = *(const bf16x8*)(xsrc + 8);
  *(bf16x8*)&sW[0][soff] = *(const bf16x8*)(wsrc);
  *(bf16x8*)&sW[0][soff + 8] = *(const bf16x8*)(wsrc + 8);
  __syncthreads();

  int cur = 0;
  for (int s = 0; s < 8; ++s) {
    bf16x8 px0, px1, pw0, pw1;
    const bool pf = (s < 7);
    if (pf) {
      const int k = (s + 1) * 64;
      px0 = *(const bf16x8*)(xsrc + k);
      px1 = *(const bf16x8*)(xsrc + k + 8);
      pw0 = *(const bf16x8*)(wsrc + k);
      pw1 = *(const bf16x8*)(wsrc + k + 8);
    }
#pragma unroll
    for (int kk = 0; kk < 2; ++kk) {
      bf16x8 a = *(const bf16x8*)&sX[cur][(wid * 16 + l15) * 72 + kk * 32 + l4 * 8];
#pragma unroll
      for (int tn = 0; tn < 4; ++tn) {
        bf16x8 b = *(const bf16x8*)&sW[cur][(tn * 16 + l15) * 72 + kk * 32 + l4 * 8];
        acc[tn] =
            __builtin_amdgcn_mfma_f32_16x16x32_bf16(a, b, acc[tn], 0, 0, 0);
      }
    }
    if (pf) {
      *(bf16x8*)&sX[cur ^ 1][soff] = px0;
      *(bf16x8*)&sX[cur ^ 1][soff + 8] = px1;
      *(bf16x8*)&sW[cur ^ 1][soff] = pw0;
      *(bf16x8*)&sW[cur ^ 1][soff + 8] = pw1;
      __syncthreads();
      cur ^= 1;
    }
  }

  // epilogue: bf16 feats stores + fused score dot-products
  float aS[4], aN[4];
#pragma unroll
  for (int tn = 0; tn < 4; ++tn) {
    aS[tn] = a_self[h * FHD + tn * 16 + l15];
    aN[tn] = a_neigh[h * FHD + tn * 16 + l15];
  }
#pragma unroll
  for (int r = 0; r < 4; ++r) {
    const int grow = n0 + wid * 16 + l4 * 4 + r;
#pragma unroll
    for (int tn = 0; tn < 4; ++tn)
      featsb[(size_t)grow * C_OUT + h * FHD + tn * 16 + l15] =
          f2bf(acc[tn][r]);
    float ps = 0.f, pn = 0.f;
#pragma unroll
    for (int tn = 0; tn < 4; ++tn) {
      float v = acc[tn][r];
      ps = fmaf(v, aS[tn], ps);
      pn = fmaf(v, aN[tn], pn);
    }
#pragma unroll
    for (int sh = 1; sh < 16; sh <<= 1) {
      ps += __shfl_xor(ps, sh, 64);
      pn += __shfl_xor(pn, sh, 64);
    }
    if (l15 == 0) {
      s_self[grow * 8 + h] = ps;
      s_neigh[grow * 8 + h] = pn;
    }
  }

  // fused colsum partials -> 64 atomicAdds/block
  float psum[4];
#pragma unroll
  for (int tn = 0; tn < 4; ++tn) {
    float s = acc[tn][0] + acc[tn][1] + acc[tn][2] + acc[tn][3];
    s += __shfl_xor(s, 16, 64);
    s += __shfl_xor(s, 32, 64);
    psum[tn] = s;
  }
  __syncthreads();  // sred was scan-aliased; also orders with MFMA loop
  if (l4 == 0) {
#pragma unroll
    for (int tn = 0; tn < 4; ++tn) sred[wid][tn * 16 + l15] = psum[tn];
  }
  __syncthreads();
  if (tid < 64) {
    float s = sred[0][tid] + sred[1][tid] + sred[2][tid] + sred[3][tid];
    atomicAdd(&colsum[h * FHD + tid], s);
  }
}

// ---------------------------------------------------------------------------
// attn: one block (256 thr) per row i; CSR pre-built.
// ---------------------------------------------------------------------------
__global__ __launch_bounds__(256) void attn_kernel(
    const unsigned short* __restrict__ edges, const int* __restrict__ degs,
    const unsigned short* __restrict__ featsb,
    const float* __restrict__ s_self, const float* __restrict__ s_neigh,
    const float* __restrict__ colsum, const float* __restrict__ bias,
    float* __restrict__ out) {
  const int i = blockIdx.x;
  const int tid = threadIdx.x;
  const int wid = tid >> 6, lane = tid & 63;
  __shared__ int s_idx[MAXE];
  __shared__ float s_w[MAXE][9];
  __shared__ float sh_self[8];
  __shared__ float sh_e0[8], sh_invZ[8];

  const int deg = degs[i];
  if (tid < 8) sh_self[tid] = s_self[i * 8 + tid];
  if (tid < deg) s_idx[tid] = edges[(size_t)i * MAXE + tid];
  __syncthreads();

  // Phase 2: raw LeakyReLU logits per (edge, head)
  for (int k = tid; k < deg * 8; k += 256) {
    int e = k >> 3, h = k & 7;
    int j = s_idx[e];
    float l = sh_self[h] + s_neigh[j * 8 + h];
    s_w[e][h] = l > 0.f ? l : ALPHA * l;
  }
  __syncthreads();

  // Phase 3: per-head softmax stats; wave wid owns heads 2wid, 2wid+1
#pragma unroll
  for (int p = 0; p < 2; ++p) {
    const int h = wid * 2 + p;
    float m = -1e30f;
    for (int e = lane; e < deg; e += 64) m = fmaxf(m, s_w[e][h]);
#pragma unroll
    for (int s = 32; s > 0; s >>= 1) m = fmaxf(m, __shfl_xor(m, s, 64));
    m = fmaxf(m, 0.0f);  // non-edge dense entries are exactly 0
    float e0 = __expf(-m);
    float zs = 0.f;
    for (int e = lane; e < deg; e += 64) {
      float w = __expf(s_w[e][h] - m);
      s_w[e][h] = w - e0;  // edge weight minus colsum-correction share
      zs += w;
    }
#pragma unroll
    for (int s = 32; s > 0; s >>= 1) zs += __shfl_xor(zs, s, 64);
    if (lane == 0) {
      sh_e0[h] = e0;
      sh_invZ[h] = 1.0f / (zs + (float)(N_NODES - deg) * e0);
    }
  }
  __syncthreads();

  // Phase 4: thread owns columns (2tid, 2tid+1); 8 FMA chains, unroll 4
  const int h = tid >> 5;
  const float e0 = sh_e0[h], invZ = sh_invZ[h];
  const float2 cs = *reinterpret_cast<const float2*>(&colsum[tid * 2]);
  const ushort2* __restrict__ fb = reinterpret_cast<const ushort2*>(featsb);
  float ax0 = e0 * cs.x, ay0 = e0 * cs.y;
  float ax1 = 0.f, ay1 = 0.f, ax2 = 0.f, ay2 = 0.f, ax3 = 0.f, ay3 = 0.f;
  int e = 0;
  for (; e + 3 < deg; e += 4) {
    int j0 = s_idx[e], j1 = s_idx[e + 1], j2 = s_idx[e + 2], j3 = s_idx[e + 3];
    float w0 = s_w[e][h], w1 = s_w[e + 1][h];
    float w2 = s_w[e + 2][h], w3 = s_w[e + 3][h];
    ushort2 u0 = fb[(size_t)j0 * 256 + tid];
    ushort2 u1 = fb[(size_t)j1 * 256 + tid];
    ushort2 u2 = fb[(size_t)j2 * 256 + tid];
    ushort2 u3 = fb[(size_t)j3 * 256 + tid];
    ax0 = fmaf(w0, bf2f(u0.x), ax0);
    ay0 = fmaf(w0, bf2f(u0.y), ay0);
    ax1 = fmaf(w1, bf2f(u1.x), ax1);
    ay1 = fmaf(w1, bf2f(u1.y), ay1);
    ax2 = fmaf(w2, bf2f(u2.x), ax2);
    ay2 = fmaf(w2, bf2f(u2.y), ay2);
    ax3 = fmaf(w3, bf2f(u3.x), ax3);
    ay3 = fmaf(w3, bf2f(u3.y), ay3);
  }
  for (; e < deg; ++e) {
    float w0 = s_w[e][h];
    ushort2 u0 = fb[(size_t)s_idx[e] * 256 + tid];
    ax0 = fmaf(w0, bf2f(u0.x), ax0);
    ay0 = fmaf(w0, bf2f(u0.y), ay0);
  }
  const float2 bb = *reinterpret_cast<const float2*>(&bias[tid * 2]);
  float vx = ((ax0 + ax1) + (ax2 + ax3)) * invZ + bb.x;
  float vy = ((ay0 + ay1) + (ay2 + ay3)) * invZ + bb.y;
  float2 o;
  o.x = vx > 0.f ? vx : 0.f;
  o.y = vy > 0.f ? vy : 0.f;
  *reinterpret_cast<float2*>(&out[(size_t)i * C_OUT + tid * 2]) = o;
}

extern "C" void kernel_launch(void* const* d_in, const int* in_sizes, int n_in,
                              void* d_out, int out_size, void* d_ws, size_t ws_size,
                              hipStream_t stream) {
  const float* X = (const float*)d_in[0];
  const float* A = (const float*)d_in[1];
  const float* W = (const float*)d_in[2];
  const float* a_self = (const float*)d_in[3];
  const float* a_neigh = (const float*)d_in[4];
  const float* b = (const float*)d_in[5];
  float* out = (float*)d_out;

  char* ws = (char*)d_ws;
  unsigned short* featsb = (unsigned short*)ws;               // 4 MB
  char* p = ws + (size_t)N_NODES * C_OUT * 2;
  float* s_self = (float*)p;  p += N_NODES * H_HEADS * 4;     // 128 KB
  float* s_neigh = (float*)p; p += N_NODES * H_HEADS * 4;     // 128 KB
  float* colsum = (float*)p;  p += C_OUT * 4;                 // 2 KB
  int* degs = (int*)p;        p += N_NODES * 4;               // 16 KB
  unsigned short* edges = (unsigned short*)p;
  p += (size_t)N_NODES * MAXE * 2;                            // 1.5 MB
  unsigned short* WbT = (unsigned short*)p;                   // 512 KB

  // Xb parked in d_out (4 MB of its 8 MB); attn fully overwrites d_out later.
  unsigned short* Xb = (unsigned short*)d_out;

  conv_kernel<<<2048 + 64 + 1, 256, 0, stream>>>(X, W, Xb, WbT, colsum);
  gemm_scan_kernel<<<GEMM_BLOCKS + N_NODES, 256, 0, stream>>>(
      Xb, WbT, a_self, a_neigh, A, featsb, s_self, s_neigh, colsum, edges,
      degs);
  attn_kernel<<<N_NODES, 256, 0, stream>>>(edges, degs, featsb, s_self,
                                           s_neigh, colsum, b, out);
}